// Round 12
// baseline (351.193 us; speedup 1.0000x reference)
//
#include <hip/hip_runtime.h>
#include <math.h>

// Problem constants (reference: B,P,NTIME,NLATENT,NSPATIAL = 4,2,16,32,2048)
#define NB 4
#define NP 2
#define NT 16
#define NC 32
#define NX 2048

// Exact triangle packing: per e, 136 floats. Row A holds S[A,j], j=0..15-A:
// S[A,0]=G[A,A], S[A,j]=G[A,A+j]+G[A+j,A]. Row offset = A*16 - A(A-1)/2.
#define TRI_N 136

// ---------------------------------------------------------------------------
// Merged precompute (single launch to cut graph-gap overhead):
//  blocks [0,512)    : G0p[c,e]  packed-symmetric (c=bid>>4, e=bid&15)
//  blocks [512,528)  : G1p[e]    packed-symmetric
//  blocks [528,544)  : M1t       (4096 elems)
//  blocks [544,1056) : M2        (131072 elems)
// ---------------------------------------------------------------------------
__device__ void g_body(const float* __restrict__ K,
                       const float* __restrict__ V,
                       const float* __restrict__ enc,
                       float* __restrict__ Gp,
                       int cstride, int c, int e, int tid) {
    __shared__ float sK[256], sV[256], sE[256], sW[256];
    {
        const int t = tid >> 4, A = tid & 15;
        sK[tid] = K[(t * 16 + A) * cstride + c];
        sV[tid] = V[(t * 16 + A) * cstride + c];
        sE[tid] = enc[(e * 16 + t) * 16 + A];
    }
    __syncthreads();
    {   // W[t,B] = sum_T enc[e,t,T] * V[T,B,c]
        const int t = tid >> 4, Bi = tid & 15;
        float acc = 0.f;
#pragma unroll
        for (int T = 0; T < 16; ++T) acc += sE[t * 16 + T] * sV[T * 16 + Bi];
        sW[tid] = acc;
    }
    __syncthreads();
    float gval;
    {   // G[A,B] = sum_t K[t,A,c] * W[t,B]
        const int A = tid >> 4, Bi = tid & 15;
        float acc = 0.f;
#pragma unroll
        for (int t = 0; t < 16; ++t) acc += sK[t * 16 + A] * sW[t * 16 + Bi];
        gval = acc;
    }
    __syncthreads();
    sE[tid] = gval;            // sE := full G tile
    __syncthreads();
    if (tid < TRI_N) {
        int A = 0, off = 0;
        while (A < 15 && tid >= off + (16 - A)) { off += 16 - A; ++A; }
        const int j = tid - off;
        const float v = (j == 0) ? sE[A * 16 + A]
                                 : sE[A * 16 + A + j] + sE[(A + j) * 16 + A];
        Gp[(c * 16 + e) * TRI_N + tid] = v;
    }
}

__global__ void precompute_all(const float* __restrict__ K0,
                               const float* __restrict__ V0,
                               const float* __restrict__ K1,
                               const float* __restrict__ V1,
                               const float* __restrict__ Q0,
                               const float* __restrict__ Q1,
                               const float* __restrict__ enc,
                               const float* __restrict__ dec,
                               float* __restrict__ G0p,
                               float* __restrict__ G1p,
                               float* __restrict__ M1t,
                               float* __restrict__ M2) {
    const int b = blockIdx.x;
    const int tid = threadIdx.x;
    if (b < 512) {
        g_body(K0, V0, enc, G0p, NC, b >> 4, b & 15, tid);
    } else if (b < 528) {
        g_body(K1, V1, enc, G1p, 1, 0, b - 512, tid);
    } else if (b < 544) {
        // M1t[e][E][T] = sum_t Q1[t,T] * dec[e,t,E]
        const int idx = (b - 528) * 256 + tid;           // 4096
        const int e = idx >> 8, E = (idx >> 4) & 15, T = idx & 15;
        float acc = 0.f;
#pragma unroll
        for (int t = 0; t < 16; ++t)
            acc += Q1[t * 16 + T] * dec[(e * 16 + t) * 16 + E];
        M1t[idx] = acc;
    } else {
        // M2[c][T][A][E] = sum_t Q0[t,A,c] * dec[E,t,T]
        const int idx = (b - 544) * 256 + tid;           // 131072
        const int c = idx >> 12, T = (idx >> 8) & 15,
                  A = (idx >> 4) & 15, E = idx & 15;
        float acc = 0.f;
#pragma unroll
        for (int t = 0; t < 16; ++t)
            acc += Q0[(t * 16 + A) * NC + c] * dec[(E * 16 + t) * 16 + T];
        M2[idx] = acc;
    }
}

__device__ __forceinline__ float sqrt_act(float v) {
    return copysignf(sqrtf(fabsf(v)), v);
}

// Broadcast weight float K (compile-time index) out of a lane-distributed
// float4 chunk: lane l holds floats [4l..4l+3]; v_readlane -> SGPR, shared
// by all lanes at zero replication cost. K must be a literal after unroll.
__device__ __forceinline__ float rl(float v, int lane) {
    return __builtin_bit_cast(float,
        __builtin_amdgcn_readlane(__builtin_bit_cast(int, v), lane));
}
#define RLW(CH, K) rl(((const float*)&(CH))[(K) & 3], (K) >> 2)

// Triangular bilinear form, weights via readlane from chunk CH (136 packed
// floats in lanes 0..33). TWO sites = 2 independent FMA chains per row
// (plus even/odd outer split = 4 chains total).
#define TRIFORM_RL2(CH, V0, V1, R0, R1)                                    \
    do {                                                                   \
        float tc0 = 0.f, td0 = 0.f, tc1 = 0.f, td1 = 0.f;                  \
        _Pragma("unroll")                                                  \
        for (int A = 0; A < 16; ++A) {                                     \
            const int koff = A * 16 - (A * (A - 1)) / 2;                   \
            float ta0 = 0.f, ta1 = 0.f;                                    \
            _Pragma("unroll")                                              \
            for (int j = 0; j < 16 - A; ++j) {                             \
                const float rw = RLW(CH, koff + j);                        \
                ta0 += rw * V0[A + j];  ta1 += rw * V1[A + j];             \
            }                                                              \
            if (A & 1) { td0 += V0[A] * ta0; td1 += V1[A] * ta1; }         \
            else       { tc0 += V0[A] * ta0; tc1 += V1[A] * ta1; }         \
        }                                                                  \
        R0 = tc0 + td0;  R1 = tc1 + td1;                                   \
    } while (0)

// ---------------------------------------------------------------------------
// Main kernel: one thread per TWO (b,p,c,x) sites (x0, x0+256).
// Weight delivery: lane-distributed global_load_dwordx4 + v_readlane
// broadcast (R10/R11 mechanism — no LDS, no barriers, no lgkmcnt drain).
// R11 post-mortem: VALU-issue-bound at ~59% per-SIMD efficiency with
// 4 waves/SIMD; this round unrolls the fused-stage and stage-3 outer
// loops x2 to interleave two iterations' readlane+FMA streams (ILP),
// keeping VGPR <= 128 so occupancy stays 4 waves/SIMD.
// grid = NB*NP*NC*(NX/512) = 1024 blocks of 256 = 4 blocks/CU.
// ---------------------------------------------------------------------------
__global__ __launch_bounds__(256) void site_kernel(
    const float* __restrict__ x,
    const float* __restrict__ a,
    const float* __restrict__ w,
    const float* __restrict__ G0p,
    const float* __restrict__ G1p,
    const float* __restrict__ M1t,
    const float* __restrict__ M2,
    float* __restrict__ out) {
    const int tid = threadIdx.x;
    const int lane = tid & 63;
    const int bid = blockIdx.x;
    const int xc = bid & 3;
    const int c  = (bid >> 2) & 31;
    const int bp = bid >> 7;              // [0, NB*NP)
    const int x0 = (xc << 9) + tid;       // site 0; site 1 at x0+256
    const float* xb = x + (bp * NT * NC + c) * NX;

    // ---- load both sites' 16-vectors (coalesced) ----
    float X0[16], X1[16];
#pragma unroll
    for (int t = 0; t < 16; ++t) {
        X0[t] = xb[t * NC * NX + x0];
        X1[t] = xb[t * NC * NX + x0 + 256];
    }

    // ======== stage 0: h[e] = sqrt_act( X^T Sym(G0[c,e]) X ) ========
    // e-block = 136 floats = 34 float4; chunk load per e, double-buffered.
    float h0[16], h1[16];
    {
        const float4* gs = (const float4*)(G0p + c * (16 * TRI_N));
        float4 cur = gs[lane];
#pragma unroll 2
        for (int e = 0; e < 16; ++e) {
            const float4 nxt = gs[((e + 1) & 15) * 34 + lane];
            float r0, r1;
            TRIFORM_RL2(cur, X0, X1, r0, r1);
            h0[e] = sqrt_act(r0);
            h1[e] = sqrt_act(r1);
            cur = nxt;
        }
    }
    // X dead here (re-loaded for the final stage).

    // ======== stages 1+2 fused:
    //   p_e = a[e,x] * sqrt_act( h^T Sym(G1[e]) h )
    //   b2[E] += p_e * ( sum_T h_T * M1t[e,E,T] )
    float b20[16], b21[16];
#pragma unroll
    for (int E = 0; E < 16; ++E) { b20[E] = 0.f; b21[E] = 0.f; }
    {
        const float4* gs = (const float4*)G1p;
        const float4* ms = (const float4*)M1t;
        float4 curG = gs[lane];
        float4 curM = ms[lane];
#pragma unroll 2
        for (int e = 0; e < 16; ++e) {
            const float4 nxtG = gs[((e + 1) & 15) * 34 + lane];
            const float4 nxtM = ms[((e + 1) & 15) * 64 + lane];
            const float ae0 = a[e * NX + x0];
            const float ae1 = a[e * NX + x0 + 256];
            float r0, r1;
            TRIFORM_RL2(curG, h0, h1, r0, r1);
            const float pe0 = ae0 * sqrt_act(r0);
            const float pe1 = ae1 * sqrt_act(r1);
#pragma unroll
            for (int E = 0; E < 16; ++E) {
                float s0 = 0.f, s1 = 0.f;
#pragma unroll
                for (int T = 0; T < 16; ++T) {
                    const float rw = RLW(curM, E * 16 + T);
                    s0 += rw * h0[T];  s1 += rw * h1[T];
                }
                b20[E] += pe0 * s0;
                b21[E] += pe1 * s1;
            }
            curG = nxtG;
            curM = nxtM;
        }
    }
    // h dead here.

    // ---- memory fence: stop Y-reload CSE keeping X alive (R6 spill cause) ----
    asm volatile("" ::: "memory");
    const float* xr = xb;
    asm volatile("" : "+r"(xr));
    float Y0[16], Y1[16];
#pragma unroll
    for (int t = 0; t < 16; ++t) {
        Y0[t] = xr[t * NC * NX + x0];
        Y1[t] = xr[t * NC * NX + x0 + 256];
    }

    // ======== stage 3: y = sum_T w[T,x] * ( Y^T M2[c,T] b2 ) ========
    float y0 = 0.f, y1 = 0.f;
    {
        const float4* ms = (const float4*)(M2 + c * 4096);
        float4 cur = ms[lane];
#pragma unroll 2
        for (int T = 0; T < 16; ++T) {
            const float4 nxt = ms[((T + 1) & 15) * 64 + lane];
            const float wt0 = w[T * NX + x0];
            const float wt1 = w[T * NX + x0 + 256];
            float c0 = 0.f, d0 = 0.f, c1 = 0.f, d1 = 0.f;
#pragma unroll
            for (int A = 0; A < 16; ++A) {
                float s0 = 0.f, s1 = 0.f;
#pragma unroll
                for (int E = 0; E < 16; ++E) {
                    const float rw = RLW(cur, A * 16 + E);
                    s0 += rw * b20[E];  s1 += rw * b21[E];
                }
                if (A & 1) { d0 += Y0[A] * s0; d1 += Y1[A] * s1; }
                else       { c0 += Y0[A] * s0; c1 += Y1[A] * s1; }
            }
            y0 += wt0 * (c0 + d0);
            y1 += wt1 * (c1 + d1);
            cur = nxt;
        }
    }

    // ---- reduce over the block, one atomic per block ----
    float y = y0 + y1;
#pragma unroll
    for (int off = 32; off > 0; off >>= 1) y += __shfl_down(y, off);
    __shared__ float red[4];
    if ((tid & 63) == 0) red[tid >> 6] = y;
    __syncthreads();
    if (tid == 0) {
        atomicAdd(&out[bp * NC + c], red[0] + red[1] + red[2] + red[3]);
    }
}

extern "C" void kernel_launch(void* const* d_in, const int* in_sizes, int n_in,
                              void* d_out, int out_size, void* d_ws, size_t ws_size,
                              hipStream_t stream) {
    const float* x   = (const float*)d_in[0];
    const float* K0  = (const float*)d_in[1];
    const float* Q0  = (const float*)d_in[2];
    const float* V0  = (const float*)d_in[3];
    const float* K1  = (const float*)d_in[4];
    const float* Q1  = (const float*)d_in[5];
    const float* V1  = (const float*)d_in[6];
    const float* enc = (const float*)d_in[7];
    const float* dec = (const float*)d_in[8];
    const float* a   = (const float*)d_in[9];
    const float* w   = (const float*)d_in[10];
    float* out = (float*)d_out;

    float* G0p = (float*)d_ws;                // 32*16*136 = 69632 floats
    float* G1p = G0p + NC * 16 * TRI_N;       // 16*136 = 2176
    float* M1t = G1p + 16 * TRI_N;            // 4096
    float* M2  = M1t + 4096;                  // 131072
    // total ws: 206976 floats ~= 0.83 MB (plus harmless prefetch overread)

    // out must be zeroed every call (harness re-poisons with 0xAA)
    hipMemsetAsync(d_out, 0, (size_t)out_size * sizeof(float), stream);

    precompute_all<<<1056, 256, 0, stream>>>(K0, V0, K1, V1, Q0, Q1,
                                             enc, dec, G0p, G1p, M1t, M2);

    const int nblocks = NB * NP * NC * (NX / 512);  // 1024
    site_kernel<<<nblocks, 256, 0, stream>>>(x, a, w, G0p, G1p, M1t, M2, out);
}

// Round 13
// 304.088 us; speedup vs baseline: 1.1549x; 1.1549x over previous
//
#include <hip/hip_runtime.h>
#include <math.h>

// Problem constants (reference: B,P,NTIME,NLATENT,NSPATIAL = 4,2,16,32,2048)
#define NB 4
#define NP 2
#define NT 16
#define NC 32
#define NX 2048

// Exact triangle packing: per e, 136 floats. Row A holds S[A,j], j=0..15-A:
// S[A,0]=G[A,A], S[A,j]=G[A,A+j]+G[A+j,A]. Row offset = A*16 - A(A-1)/2.
#define TRI_N 136

// ---------------------------------------------------------------------------
// Merged precompute (single launch; R12 measured: cuts launch overhead
// from ~69us to ~17us vs 4 separate launches):
//  blocks [0,512)    : G0p[c,e]  packed-symmetric (c=bid>>4, e=bid&15)
//  blocks [512,528)  : G1p[e]    packed-symmetric
//  blocks [528,544)  : M1t       (4096 elems)
//  blocks [544,1056) : M2        (131072 elems)
// ---------------------------------------------------------------------------
__device__ void g_body(const float* __restrict__ K,
                       const float* __restrict__ V,
                       const float* __restrict__ enc,
                       float* __restrict__ Gp,
                       int cstride, int c, int e, int tid) {
    __shared__ float sK[256], sV[256], sE[256], sW[256];
    {
        const int t = tid >> 4, A = tid & 15;
        sK[tid] = K[(t * 16 + A) * cstride + c];
        sV[tid] = V[(t * 16 + A) * cstride + c];
        sE[tid] = enc[(e * 16 + t) * 16 + A];
    }
    __syncthreads();
    {   // W[t,B] = sum_T enc[e,t,T] * V[T,B,c]
        const int t = tid >> 4, Bi = tid & 15;
        float acc = 0.f;
#pragma unroll
        for (int T = 0; T < 16; ++T) acc += sE[t * 16 + T] * sV[T * 16 + Bi];
        sW[tid] = acc;
    }
    __syncthreads();
    float gval;
    {   // G[A,B] = sum_t K[t,A,c] * W[t,B]
        const int A = tid >> 4, Bi = tid & 15;
        float acc = 0.f;
#pragma unroll
        for (int t = 0; t < 16; ++t) acc += sK[t * 16 + A] * sW[t * 16 + Bi];
        gval = acc;
    }
    __syncthreads();
    sE[tid] = gval;            // sE := full G tile
    __syncthreads();
    if (tid < TRI_N) {
        int A = 0, off = 0;
        while (A < 15 && tid >= off + (16 - A)) { off += 16 - A; ++A; }
        const int j = tid - off;
        const float v = (j == 0) ? sE[A * 16 + A]
                                 : sE[A * 16 + A + j] + sE[(A + j) * 16 + A];
        Gp[(c * 16 + e) * TRI_N + tid] = v;
    }
}

__global__ void precompute_all(const float* __restrict__ K0,
                               const float* __restrict__ V0,
                               const float* __restrict__ K1,
                               const float* __restrict__ V1,
                               const float* __restrict__ Q0,
                               const float* __restrict__ Q1,
                               const float* __restrict__ enc,
                               const float* __restrict__ dec,
                               float* __restrict__ G0p,
                               float* __restrict__ G1p,
                               float* __restrict__ M1t,
                               float* __restrict__ M2) {
    const int b = blockIdx.x;
    const int tid = threadIdx.x;
    if (b < 512) {
        g_body(K0, V0, enc, G0p, NC, b >> 4, b & 15, tid);
    } else if (b < 528) {
        g_body(K1, V1, enc, G1p, 1, 0, b - 512, tid);
    } else if (b < 544) {
        // M1t[e][E][T] = sum_t Q1[t,T] * dec[e,t,E]
        const int idx = (b - 528) * 256 + tid;           // 4096
        const int e = idx >> 8, E = (idx >> 4) & 15, T = idx & 15;
        float acc = 0.f;
#pragma unroll
        for (int t = 0; t < 16; ++t)
            acc += Q1[t * 16 + T] * dec[(e * 16 + t) * 16 + E];
        M1t[idx] = acc;
    } else {
        // M2[c][T][A][E] = sum_t Q0[t,A,c] * dec[E,t,T]
        const int idx = (b - 544) * 256 + tid;           // 131072
        const int c = idx >> 12, T = (idx >> 8) & 15,
                  A = (idx >> 4) & 15, E = idx & 15;
        float acc = 0.f;
#pragma unroll
        for (int t = 0; t < 16; ++t)
            acc += Q0[(t * 16 + A) * NC + c] * dec[(E * 16 + t) * 16 + T];
        M2[idx] = acc;
    }
}

__device__ __forceinline__ float sqrt_act(float v) {
    return copysignf(sqrtf(fabsf(v)), v);
}

// Broadcast weight float K (compile-time index) out of a lane-distributed
// float4 chunk: lane l holds floats [4l..4l+3]; v_readlane -> SGPR, shared
// by all lanes at zero replication cost. K must be a literal after unroll.
__device__ __forceinline__ float rl(float v, int lane) {
    return __builtin_bit_cast(float,
        __builtin_amdgcn_readlane(__builtin_bit_cast(int, v), lane));
}
#define RLW(CH, K) rl(((const float*)&(CH))[(K) & 3], (K) >> 2)

// Triangular bilinear form, weights via readlane from chunk CH (136 packed
// floats in lanes 0..33). TWO sites = 2 independent FMA chains per row
// (plus even/odd outer split = 4 chains total).
#define TRIFORM_RL2(CH, V0, V1, R0, R1)                                    \
    do {                                                                   \
        float tc0 = 0.f, td0 = 0.f, tc1 = 0.f, td1 = 0.f;                  \
        _Pragma("unroll")                                                  \
        for (int A = 0; A < 16; ++A) {                                     \
            const int koff = A * 16 - (A * (A - 1)) / 2;                   \
            float ta0 = 0.f, ta1 = 0.f;                                    \
            _Pragma("unroll")                                              \
            for (int j = 0; j < 16 - A; ++j) {                             \
                const float rw = RLW(CH, koff + j);                        \
                ta0 += rw * V0[A + j];  ta1 += rw * V1[A + j];             \
            }                                                              \
            if (A & 1) { td0 += V0[A] * ta0; td1 += V1[A] * ta1; }         \
            else       { tc0 += V0[A] * ta0; tc1 += V1[A] * ta1; }         \
        }                                                                  \
        R0 = tc0 + td0;  R1 = tc1 + td1;                                   \
    } while (0)

// ---------------------------------------------------------------------------
// Main kernel: one thread per TWO (b,p,c,x) sites (x0, x0+256).
// Weight delivery: lane-distributed global_load_dwordx4 + v_readlane
// broadcast (R10/R11 mechanism — no LDS, no barriers, no lgkmcnt drain).
// EXACT R11 configuration (best known: 241us site, VGPR=100, 4 waves/SIMD):
// stage-0 outer unroll 2; fused stage + stage 3 outer unroll 1.
// R12 lesson locked in: unrolling the big stages x2 pushes VGPR to 136
// (>128) -> 3 waves/SIMD -> 334us. At this operating point occupancy > ILP.
// grid = NB*NP*NC*(NX/512) = 1024 blocks of 256 = 4 blocks/CU.
// ---------------------------------------------------------------------------
__global__ __launch_bounds__(256) void site_kernel(
    const float* __restrict__ x,
    const float* __restrict__ a,
    const float* __restrict__ w,
    const float* __restrict__ G0p,
    const float* __restrict__ G1p,
    const float* __restrict__ M1t,
    const float* __restrict__ M2,
    float* __restrict__ out) {
    const int tid = threadIdx.x;
    const int lane = tid & 63;
    const int bid = blockIdx.x;
    const int xc = bid & 3;
    const int c  = (bid >> 2) & 31;
    const int bp = bid >> 7;              // [0, NB*NP)
    const int x0 = (xc << 9) + tid;       // site 0; site 1 at x0+256
    const float* xb = x + (bp * NT * NC + c) * NX;

    // ---- load both sites' 16-vectors (coalesced) ----
    float X0[16], X1[16];
#pragma unroll
    for (int t = 0; t < 16; ++t) {
        X0[t] = xb[t * NC * NX + x0];
        X1[t] = xb[t * NC * NX + x0 + 256];
    }

    // ======== stage 0: h[e] = sqrt_act( X^T Sym(G0[c,e]) X ) ========
    // e-block = 136 floats = 34 float4; chunk load per e, double-buffered.
    float h0[16], h1[16];
    {
        const float4* gs = (const float4*)(G0p + c * (16 * TRI_N));
        float4 cur = gs[lane];
#pragma unroll 2
        for (int e = 0; e < 16; ++e) {
            const float4 nxt = gs[((e + 1) & 15) * 34 + lane];
            float r0, r1;
            TRIFORM_RL2(cur, X0, X1, r0, r1);
            h0[e] = sqrt_act(r0);
            h1[e] = sqrt_act(r1);
            cur = nxt;
        }
    }
    // X dead here (re-loaded for the final stage).

    // ======== stages 1+2 fused:
    //   p_e = a[e,x] * sqrt_act( h^T Sym(G1[e]) h )
    //   b2[E] += p_e * ( sum_T h_T * M1t[e,E,T] )
    float b20[16], b21[16];
#pragma unroll
    for (int E = 0; E < 16; ++E) { b20[E] = 0.f; b21[E] = 0.f; }
    {
        const float4* gs = (const float4*)G1p;
        const float4* ms = (const float4*)M1t;
        float4 curG = gs[lane];
        float4 curM = ms[lane];
#pragma unroll 1
        for (int e = 0; e < 16; ++e) {
            const float4 nxtG = gs[((e + 1) & 15) * 34 + lane];
            const float4 nxtM = ms[((e + 1) & 15) * 64 + lane];
            const float ae0 = a[e * NX + x0];
            const float ae1 = a[e * NX + x0 + 256];
            float r0, r1;
            TRIFORM_RL2(curG, h0, h1, r0, r1);
            const float pe0 = ae0 * sqrt_act(r0);
            const float pe1 = ae1 * sqrt_act(r1);
#pragma unroll
            for (int E = 0; E < 16; ++E) {
                float s0 = 0.f, s1 = 0.f;
#pragma unroll
                for (int T = 0; T < 16; ++T) {
                    const float rw = RLW(curM, E * 16 + T);
                    s0 += rw * h0[T];  s1 += rw * h1[T];
                }
                b20[E] += pe0 * s0;
                b21[E] += pe1 * s1;
            }
            curG = nxtG;
            curM = nxtM;
        }
    }
    // h dead here.

    // ---- memory fence: stop Y-reload CSE keeping X alive (R6 spill cause) ----
    asm volatile("" ::: "memory");
    const float* xr = xb;
    asm volatile("" : "+r"(xr));
    float Y0[16], Y1[16];
#pragma unroll
    for (int t = 0; t < 16; ++t) {
        Y0[t] = xr[t * NC * NX + x0];
        Y1[t] = xr[t * NC * NX + x0 + 256];
    }

    // ======== stage 3: y = sum_T w[T,x] * ( Y^T M2[c,T] b2 ) ========
    float y0 = 0.f, y1 = 0.f;
    {
        const float4* ms = (const float4*)(M2 + c * 4096);
        float4 cur = ms[lane];
#pragma unroll 1
        for (int T = 0; T < 16; ++T) {
            const float4 nxt = ms[((T + 1) & 15) * 64 + lane];
            const float wt0 = w[T * NX + x0];
            const float wt1 = w[T * NX + x0 + 256];
            float c0 = 0.f, d0 = 0.f, c1 = 0.f, d1 = 0.f;
#pragma unroll
            for (int A = 0; A < 16; ++A) {
                float s0 = 0.f, s1 = 0.f;
#pragma unroll
                for (int E = 0; E < 16; ++E) {
                    const float rw = RLW(cur, A * 16 + E);
                    s0 += rw * b20[E];  s1 += rw * b21[E];
                }
                if (A & 1) { d0 += Y0[A] * s0; d1 += Y1[A] * s1; }
                else       { c0 += Y0[A] * s0; c1 += Y1[A] * s1; }
            }
            y0 += wt0 * (c0 + d0);
            y1 += wt1 * (c1 + d1);
            cur = nxt;
        }
    }

    // ---- reduce over the block, one atomic per block ----
    float y = y0 + y1;
#pragma unroll
    for (int off = 32; off > 0; off >>= 1) y += __shfl_down(y, off);
    __shared__ float red[4];
    if ((tid & 63) == 0) red[tid >> 6] = y;
    __syncthreads();
    if (tid == 0) {
        atomicAdd(&out[bp * NC + c], red[0] + red[1] + red[2] + red[3]);
    }
}

extern "C" void kernel_launch(void* const* d_in, const int* in_sizes, int n_in,
                              void* d_out, int out_size, void* d_ws, size_t ws_size,
                              hipStream_t stream) {
    const float* x   = (const float*)d_in[0];
    const float* K0  = (const float*)d_in[1];
    const float* Q0  = (const float*)d_in[2];
    const float* V0  = (const float*)d_in[3];
    const float* K1  = (const float*)d_in[4];
    const float* Q1  = (const float*)d_in[5];
    const float* V1  = (const float*)d_in[6];
    const float* enc = (const float*)d_in[7];
    const float* dec = (const float*)d_in[8];
    const float* a   = (const float*)d_in[9];
    const float* w   = (const float*)d_in[10];
    float* out = (float*)d_out;

    float* G0p = (float*)d_ws;                // 32*16*136 = 69632 floats
    float* G1p = G0p + NC * 16 * TRI_N;       // 16*136 = 2176
    float* M1t = G1p + 16 * TRI_N;            // 4096
    float* M2  = M1t + 4096;                  // 131072
    // total ws: 206976 floats ~= 0.83 MB (plus harmless prefetch overread)

    // out must be zeroed every call (harness re-poisons with 0xAA)
    hipMemsetAsync(d_out, 0, (size_t)out_size * sizeof(float), stream);

    precompute_all<<<1056, 256, 0, stream>>>(K0, V0, K1, V1, Q0, Q1,
                                             enc, dec, G0p, G1p, M1t, M2);

    const int nblocks = NB * NP * NC * (NX / 512);  // 1024
    site_kernel<<<nblocks, 256, 0, stream>>>(x, a, w, G0p, G1p, M1t, M2, out);
}